// Round 6
// baseline (528.377 us; speedup 1.0000x reference)
//
#include <hip/hip_runtime.h>
#include <math.h>

#define NUM_K 512
#define DIM   64
#define HW    4096
#define IMG   (DIM * HW)
#define OUT_Q 8388608
#define LOSS_OFF OUT_Q
#define IDX_OFF (OUT_Q + 1)
#define NPIX  131072
#define DELTA 1.5e-4f

// ws layout (bytes)
#define WS_EH   0        // bf16 hi codebook [512*64] shorts = 64KB
#define WS_EL   65536    // bf16 lo codebook = 64KB
#define WS_SE   131072   // ||e||^2 f32 [512] = 2KB
#define WS_MASK 133120   // flag bitmask [4096 u32] = 16KB
#define WS_PART 149504   // loss partials double [512] = 4KB

typedef float f32x4 __attribute__((ext_vector_type(4)));
typedef short s8v   __attribute__((ext_vector_type(8)));

__device__ inline short f2bf(float f) {  // RNE f32->bf16
  unsigned u = __float_as_uint(f);
  return (short)((u + 0x7FFF + ((u >> 16) & 1)) >> 16);
}
__device__ inline float bf2f(short s) {
  return __uint_as_float(((unsigned)(unsigned short)s) << 16);
}

// K1: split codebook to bf16 hi/lo, ||e||^2 (proven d-ascending chain), zero mask
__global__ void vq_prep(const float* __restrict__ emb, char* __restrict__ ws) {
  short* eh = (short*)(ws + WS_EH);
  short* el = (short*)(ws + WS_EL);
  float* se = (float*)(ws + WS_SE);
  unsigned* mask = (unsigned*)(ws + WS_MASK);
  const int k = blockIdx.x * 256 + threadIdx.x;  // 0..511
#pragma unroll
  for (int i = 0; i < 8; ++i) mask[k * 8 + i] = 0u;
  const float* e = emb + k * DIM;
  float s = 0.f;
#pragma unroll
  for (int j = 0; j < DIM; ++j) {
    const float v = e[j];
    s = fmaf(v, v, s);
    const short h = f2bf(v);
    eh[k * DIM + j] = h;
    el[k * DIM + j] = f2bf(v - bf2f(h));
  }
  se[k] = s;
}

// K2: MFMA approx distances + min1/min2 track + margin flag + q/idx/loss
__launch_bounds__(256, 2)
__global__ void vq_main(const float* __restrict__ in, const float* __restrict__ emb,
                        char* __restrict__ ws, float* __restrict__ out) {
  const short* eh = (const short*)(ws + WS_EH);
  const short* el = (const short*)(ws + WS_EL);
  const float* se = (const float*)(ws + WS_SE);
  unsigned* mask = (unsigned*)(ws + WS_MASK);
  double* partial = (double*)(ws + WS_PART);
  __shared__ int bkbuf[256];
  __shared__ double red[4];

  const int tid = threadIdx.x;
  const int lane = tid & 63, w = tid >> 6;
  const int l15 = lane & 15, lh = lane >> 4;   // lh 0..3
  const int d0 = lh * 8;                        // lane's K-slice base
  const int pblk = blockIdx.x * 256;            // 256 contiguous pixels per block
  const int n = pblk >> 12;                     // uniform (256 | 4096)
  const int hwb = pblk & 4095;
  const int p0 = w * 64;                        // wave-local pixel base

  // ---- A-fragments: x[p0+rt*16+l15][h*32+d0+j] as bf16 hi/lo ----
  s8v ah[4][2], al[4][2];
#pragma unroll
  for (int rt = 0; rt < 4; ++rt) {
    const float* xp = in + (size_t)n * IMG + hwb + (p0 + rt * 16 + l15);
#pragma unroll
    for (int h = 0; h < 2; ++h) {
      s8v vh, vl;
#pragma unroll
      for (int j = 0; j < 8; ++j) {
        const float xv = xp[(h * 32 + d0 + j) * HW];
        const short hi = f2bf(xv);
        vh[j] = hi;
        vl[j] = f2bf(xv - bf2f(hi));
      }
      ah[rt][h] = vh; al[rt][h] = vl;
    }
  }

  // ---- 32 code-tiles of 16; track packed (value|code) min1/min2 ----
  float m1[4][4], m2[4][4];
#pragma unroll
  for (int rt = 0; rt < 4; ++rt)
#pragma unroll
    for (int r = 0; r < 4; ++r) { m1[rt][r] = INFINITY; m2[rt][r] = INFINITY; }

  for (int ct = 0; ct < 32; ++ct) {
    const int c = ct * 16 + l15;                 // this lane's code column
    const s8v beh0 = *(const s8v*)(eh + c * DIM + d0);
    const s8v beh1 = *(const s8v*)(eh + c * DIM + 32 + d0);
    const s8v bel0 = *(const s8v*)(el + c * DIM + d0);
    const s8v bel1 = *(const s8v*)(el + c * DIM + 32 + d0);
    const float sec = se[c];
#pragma unroll
    for (int rt = 0; rt < 4; ++rt) {
      f32x4 acc = {0.f, 0.f, 0.f, 0.f};
      acc = __builtin_amdgcn_mfma_f32_16x16x32_bf16(ah[rt][0], beh0, acc, 0, 0, 0);
      acc = __builtin_amdgcn_mfma_f32_16x16x32_bf16(ah[rt][1], beh1, acc, 0, 0, 0);
      acc = __builtin_amdgcn_mfma_f32_16x16x32_bf16(al[rt][0], beh0, acc, 0, 0, 0);
      acc = __builtin_amdgcn_mfma_f32_16x16x32_bf16(al[rt][1], beh1, acc, 0, 0, 0);
      acc = __builtin_amdgcn_mfma_f32_16x16x32_bf16(ah[rt][0], bel0, acc, 0, 0, 0);
      acc = __builtin_amdgcn_mfma_f32_16x16x32_bf16(ah[rt][1], bel1, acc, 0, 0, 0);
#pragma unroll
      for (int r = 0; r < 4; ++r) {
        const float cv = fmaf(-2.f, acc[r], sec);         // se - 2*dot
        const float pk = __int_as_float((__float_as_int(cv) & 0xFFFFFE00) | c);
        m2[rt][r] = fminf(m2[rt][r], fmaxf(m1[rt][r], pk));
        m1[rt][r] = fminf(m1[rt][r], pk);
      }
    }
  }

  // ---- reduce min1/min2 across the 16 code-column lanes ----
#pragma unroll
  for (int s = 1; s < 16; s <<= 1) {
#pragma unroll
    for (int rt = 0; rt < 4; ++rt)
#pragma unroll
      for (int r = 0; r < 4; ++r) {
        const float o1 = __shfl_xor(m1[rt][r], s);
        const float o2 = __shfl_xor(m2[rt][r], s);
        const float hi = fmaxf(m1[rt][r], o1);
        m1[rt][r] = fminf(m1[rt][r], o1);
        m2[rt][r] = fminf(fminf(m2[rt][r], o2), hi);
      }
  }
  if (l15 == 0) {
#pragma unroll
    for (int rt = 0; rt < 4; ++rt)
#pragma unroll
      for (int r = 0; r < 4; ++r) {
        const int lp = p0 + rt * 16 + lh * 4 + r;          // C-row pixel
        bkbuf[lp] = __float_as_int(m1[rt][r]) & 511;
        if (m2[rt][r] - m1[rt][r] <= DELTA) {              // ambiguous -> exact rerank
          const int p = pblk + lp;
          atomicOr(&mask[p >> 5], 1u << (p & 31));
        }
      }
  }
  __syncthreads();

  // ---- epilogue: gather q, write q/idx, loss partial ----
  float ls = 0.f;
#pragma unroll
  for (int rt = 0; rt < 4; ++rt) {
    const int lp = p0 + rt * 16 + l15;
    const int bk = bkbuf[lp];
    if (lh == 0) out[IDX_OFF + pblk + lp] = (float)bk;
    const float* ep = emb + bk * DIM;
    const float* xp = in  + (size_t)n * IMG + hwb + lp;
    float*       op = out + (size_t)n * IMG + hwb + lp;
#pragma unroll
    for (int h = 0; h < 2; ++h)
#pragma unroll
      for (int j = 0; j < 8; ++j) {
        const int d = h * 32 + d0 + j;
        const float q = ep[d];
        const float xv = xp[d * HW];
        op[d * HW] = q;
        const float dd = q - xv;
        ls = fmaf(dd, dd, ls);
      }
  }
  double dls = (double)ls;
#pragma unroll
  for (int o = 32; o; o >>= 1) dls += __shfl_down(dls, o);
  if (lane == 0) red[w] = dls;
  __syncthreads();
  if (tid == 0) partial[blockIdx.x] = red[0] + red[1] + red[2] + red[3];
}

// K3: exact fp32 rerank of flagged pixels (proven round-2..5 formula + tie-break)
__global__ void vq_fix(const float* __restrict__ in, const float* __restrict__ emb,
                       char* __restrict__ ws, float* __restrict__ out) {
  const float* se = (const float*)(ws + WS_SE);
  const unsigned* mask = (const unsigned*)(ws + WS_MASK);
  double* partial = (double*)(ws + WS_PART);
  const int lane = threadIdx.x & 63;
  const int wid = blockIdx.x * 4 + (threadIdx.x >> 6);   // 0..1023
  for (int gg = 0; gg < 2; ++gg) {
    const int g = wid + gg * 1024;                        // 64-pixel group
    const unsigned w0 = mask[g * 2], w1 = mask[g * 2 + 1];
    unsigned long long bits = ((unsigned long long)w1 << 32) | w0;
    while (bits) {
      const int b = __ffsll((long long)bits) - 1;
      bits &= bits - 1;
      const int p = g * 64 + b;
      const int n = p >> 12, hw = p & 4095;
      const float* xp = in + (size_t)n * IMG + hw;
      float xv[DIM];
#pragma unroll
      for (int j = 0; j < DIM; ++j) xv[j] = xp[j * HW];   // wave-uniform
      float sx = 0.f;
#pragma unroll
      for (int j = 0; j < DIM; ++j) sx = fmaf(xv[j], xv[j], sx);
      float bd = INFINITY; int bki = 0;
#pragma unroll
      for (int m = 0; m < 8; ++m) {
        const int k = lane + 64 * m;
        const float* ek = emb + k * DIM;
        float a = 0.f;
#pragma unroll
        for (int j = 0; j < DIM; ++j) a = fmaf(xv[j], ek[j], a);
        const float d = (sx + se[k]) - 2.f * a;
        if (d < bd) { bd = d; bki = k; }                  // ascending k in-lane
      }
#pragma unroll
      for (int s = 1; s < 64; s <<= 1) {                  // lex-min (d, k)
        const float od = __shfl_xor(bd, s);
        const int   oi = __shfl_xor(bki, s);
        const bool t = (od < bd) || (od == bd && oi < bki);
        bd = t ? od : bd; bki = t ? oi : bki;
      }
      const int oldk = (int)out[IDX_OFF + p];
      if (bki != oldk) {
        const float xj = xp[lane * HW];
        const float qn = emb[bki * DIM + lane];
        const float qo = emb[oldk * DIM + lane];
        out[(size_t)n * IMG + lane * HW + hw] = qn;
        const float dl = (qn - xj) * (qn - xj) - (qo - xj) * (qo - xj);
        double dd = (double)dl;
#pragma unroll
        for (int o = 32; o; o >>= 1) dd += __shfl_down(dd, o);
        if (lane == 0) {
          atomicAdd(&partial[0], dd);
          out[IDX_OFF + p] = (float)bki;
        }
      }
    }
  }
}

// K4: finalize loss
__global__ void vq_loss(const double* __restrict__ partial, float* __restrict__ out) {
  __shared__ double r2[4];
  const int tid = threadIdx.x;
  double s = partial[tid] + partial[tid + 256];
#pragma unroll
  for (int o = 32; o; o >>= 1) s += __shfl_down(s, o);
  if ((tid & 63) == 0) r2[tid >> 6] = s;
  __syncthreads();
  if (tid == 0) {
    const double t = r2[0] + r2[1] + r2[2] + r2[3];
    out[LOSS_OFF] = (float)(0.25 * t / (double)OUT_Q);
  }
}

extern "C" void kernel_launch(void* const* d_in, const int* in_sizes, int n_in,
                              void* d_out, int out_size, void* d_ws, size_t ws_size,
                              hipStream_t stream) {
  (void)in_sizes; (void)n_in; (void)out_size; (void)ws_size;
  const float* in  = (const float*)d_in[0];
  const float* emb = (const float*)d_in[1];
  float* out = (float*)d_out;
  char* ws = (char*)d_ws;
  vq_prep<<<2,   256, 0, stream>>>(emb, ws);
  vq_main<<<512, 256, 0, stream>>>(in, emb, ws, out);
  vq_fix <<<256, 256, 0, stream>>>(in, emb, ws, out);
  vq_loss<<<1,   256, 0, stream>>>((const double*)(ws + WS_PART), out);
}

// Round 7
// 270.656 us; speedup vs baseline: 1.9522x; 1.9522x over previous
//
#include <hip/hip_runtime.h>
#include <math.h>

#define NUM_K 512
#define DIM   64
#define HW    4096
#define IMG   (DIM * HW)
#define OUT_Q 8388608
#define LOSS_OFF OUT_Q
#define IDX_OFF (OUT_Q + 1)
#define DELTA 8e-5f

// ws layout (bytes)
#define WS_EH   0        // bf16 hi codebook [512*64] = 64KB
#define WS_EL   65536    // bf16 lo codebook = 64KB
#define WS_SE   131072   // ||e||^2 f32 [512] = 2KB
#define WS_CNT  133120   // worklist counter (int) + pad = 256B
#define WS_PART 133376   // loss partials double[512] = 4KB
#define WS_WL   137472   // worklist pixel ids (cap from ws_size)

typedef float f32x4 __attribute__((ext_vector_type(4)));
typedef short s8v   __attribute__((ext_vector_type(8)));

__device__ inline short f2bf(float f) {  // RNE f32->bf16
  unsigned u = __float_as_uint(f);
  return (short)((u + 0x7FFF + ((u >> 16) & 1)) >> 16);
}
__device__ inline float bf2f(short s) {
  return __uint_as_float(((unsigned)(unsigned short)s) << 16);
}

// K1: split codebook to bf16 hi/lo, ||e||^2, zero worklist counter
__global__ void vq_prep(const float* __restrict__ emb, char* __restrict__ ws) {
  short* eh = (short*)(ws + WS_EH);
  short* el = (short*)(ws + WS_EL);
  float* se = (float*)(ws + WS_SE);
  const int k = blockIdx.x * 256 + threadIdx.x;  // 0..511
  if (k == 0) *(int*)(ws + WS_CNT) = 0;
  const float* e = emb + k * DIM;
  float s = 0.f;
#pragma unroll
  for (int j = 0; j < DIM; ++j) {
    const float v = e[j];
    s = fmaf(v, v, s);
    const short h = f2bf(v);
    eh[k * DIM + j] = h;
    el[k * DIM + j] = f2bf(v - bf2f(h));
  }
  se[k] = s;
}

// K2: MFMA approx distances + min1/min2 + compaction + q/idx/loss + x-stash
__launch_bounds__(256, 2)
__global__ void vq_main(const float* __restrict__ in, const float* __restrict__ emb,
                        char* __restrict__ ws, float* __restrict__ out,
                        int wlcap, int wxcap, unsigned long long wxoff) {
  const short* eh = (const short*)(ws + WS_EH);
  const short* el = (const short*)(ws + WS_EL);
  const float* se = (const float*)(ws + WS_SE);
  int* wcnt  = (int*)(ws + WS_CNT);
  int* wlist = (int*)(ws + WS_WL);
  float* wx  = (float*)(ws + wxoff);
  double* partial = (double*)(ws + WS_PART);
  __shared__ int bkbuf[256];
  __shared__ int slotbuf[256];
  __shared__ unsigned char flg[256];
  __shared__ double red[4];

  const int tid = threadIdx.x;
  const int lane = tid & 63, w = tid >> 6;
  const int l15 = lane & 15, lh = lane >> 4;   // lh 0..3
  const int d0 = lh * 8;                        // lane's K-slice base
  const int pblk = blockIdx.x * 256;            // 256 contiguous pixels/block
  const int n = pblk >> 12;                     // uniform (256 | 4096)
  const int hwb = pblk & 4095;
  const int p0 = w * 64;                        // wave-local pixel base

  // ---- A-fragments: x[p0+rt*16+l15][h*32+d0+j] as bf16 hi/lo ----
  s8v ah[4][2], al[4][2];
#pragma unroll
  for (int rt = 0; rt < 4; ++rt) {
    const float* xp = in + (size_t)n * IMG + hwb + (p0 + rt * 16 + l15);
#pragma unroll
    for (int h = 0; h < 2; ++h) {
      s8v vh, vl;
#pragma unroll
      for (int j = 0; j < 8; ++j) {
        const float xv = xp[(h * 32 + d0 + j) * HW];
        const short hi = f2bf(xv);
        vh[j] = hi;
        vl[j] = f2bf(xv - bf2f(hi));
      }
      ah[rt][h] = vh; al[rt][h] = vl;
    }
  }

  // ---- 32 code-tiles of 16; packed (value|code) min1/min2 tracking ----
  float m1[4][4], m2[4][4];
#pragma unroll
  for (int rt = 0; rt < 4; ++rt)
#pragma unroll
    for (int r = 0; r < 4; ++r) { m1[rt][r] = INFINITY; m2[rt][r] = INFINITY; }

  for (int ct = 0; ct < 32; ++ct) {
    const int c = ct * 16 + l15;                 // this lane's code column
    const s8v beh0 = *(const s8v*)(eh + c * DIM + d0);
    const s8v beh1 = *(const s8v*)(eh + c * DIM + 32 + d0);
    const s8v bel0 = *(const s8v*)(el + c * DIM + d0);
    const s8v bel1 = *(const s8v*)(el + c * DIM + 32 + d0);
    const float sec = se[c];
#pragma unroll
    for (int rt = 0; rt < 4; ++rt) {
      f32x4 acc = {0.f, 0.f, 0.f, 0.f};
      acc = __builtin_amdgcn_mfma_f32_16x16x32_bf16(ah[rt][0], beh0, acc, 0, 0, 0);
      acc = __builtin_amdgcn_mfma_f32_16x16x32_bf16(ah[rt][1], beh1, acc, 0, 0, 0);
      acc = __builtin_amdgcn_mfma_f32_16x16x32_bf16(al[rt][0], beh0, acc, 0, 0, 0);
      acc = __builtin_amdgcn_mfma_f32_16x16x32_bf16(al[rt][1], beh1, acc, 0, 0, 0);
      acc = __builtin_amdgcn_mfma_f32_16x16x32_bf16(ah[rt][0], bel0, acc, 0, 0, 0);
      acc = __builtin_amdgcn_mfma_f32_16x16x32_bf16(ah[rt][1], bel1, acc, 0, 0, 0);
#pragma unroll
      for (int r = 0; r < 4; ++r) {
        const float cv = fmaf(-2.f, acc[r], sec);          // se - 2*dot
        const float pk = __int_as_float((__float_as_int(cv) & 0xFFFFFE00) | c);
        m2[rt][r] = fminf(m2[rt][r], fmaxf(m1[rt][r], pk));
        m1[rt][r] = fminf(m1[rt][r], pk);
      }
    }
  }

  // ---- reduce min1/min2 across the 16 code-column lanes ----
#pragma unroll
  for (int s = 1; s < 16; s <<= 1) {
#pragma unroll
    for (int rt = 0; rt < 4; ++rt)
#pragma unroll
      for (int r = 0; r < 4; ++r) {
        const float o1 = __shfl_xor(m1[rt][r], s);
        const float o2 = __shfl_xor(m2[rt][r], s);
        const float hi = fmaxf(m1[rt][r], o1);
        m1[rt][r] = fminf(m1[rt][r], o1);
        m2[rt][r] = fminf(fminf(m2[rt][r], o2), hi);
      }
  }
  if (l15 == 0) {
#pragma unroll
    for (int rt = 0; rt < 4; ++rt)
#pragma unroll
      for (int r = 0; r < 4; ++r) {
        const int lp = p0 + rt * 16 + lh * 4 + r;          // C-row pixel
        bkbuf[lp] = __float_as_int(m1[rt][r]) & 511;
        flg[lp] = (m2[rt][r] - m1[rt][r] <= DELTA) ? 1 : 0;
      }
  }
  __syncthreads();

  // ---- compaction: one atomicAdd per wave, slot per flagged pixel ----
  {
    const bool f = flg[tid] != 0;
    const unsigned long long b = __ballot(f);
    const int cnt = __popcll(b);
    int base = 0;
    if (cnt) {
      if (lane == 0) base = atomicAdd(wcnt, cnt);
      base = __shfl(base, 0);
    }
    int sl = -1;
    if (f) {
      const int pos = base + __popcll(b & ((1ull << lane) - 1));
      if (pos < wlcap) { sl = pos; wlist[pos] = pblk + tid; }
    }
    slotbuf[tid] = sl;
  }
  __syncthreads();

  // ---- epilogue: gather q, write q/idx, loss partial, stash flagged x ----
  float ls = 0.f;
#pragma unroll
  for (int rt = 0; rt < 4; ++rt) {
    const int lp = p0 + rt * 16 + l15;
    const int bk = bkbuf[lp];
    const int sl = slotbuf[lp];
    if (lh == 0) out[IDX_OFF + pblk + lp] = (float)bk;
    const float* ep = emb + bk * DIM;
    const float* xp = in  + (size_t)n * IMG + hwb + lp;
    float*       op = out + (size_t)n * IMG + hwb + lp;
#pragma unroll
    for (int h = 0; h < 2; ++h)
#pragma unroll
      for (int j = 0; j < 8; ++j) {
        const int d = h * 32 + d0 + j;
        const float q = ep[d];
        const float xv = xp[d * HW];
        op[d * HW] = q;
        if (sl >= 0 && sl < wxcap) wx[(size_t)sl * DIM + d] = xv;
        const float dd = q - xv;
        ls = fmaf(dd, dd, ls);
      }
  }
  double dls = (double)ls;
#pragma unroll
  for (int o = 32; o; o >>= 1) dls += __shfl_down(dls, o);
  if (lane == 0) red[w] = dls;
  __syncthreads();
  if (tid == 0) partial[blockIdx.x] = red[0] + red[1] + red[2] + red[3];
}

// K3: exact fp32 rerank of worklist pixels (proven formula + tie-break),
// one wave per pixel, grid-stride.
__global__ void vq_fix(const float* __restrict__ in, const float* __restrict__ emb,
                       char* __restrict__ ws, float* __restrict__ out,
                       int wlcap, int wxcap, unsigned long long wxoff) {
  const float* se = (const float*)(ws + WS_SE);
  const int* wlist = (const int*)(ws + WS_WL);
  const float* wx = (const float*)(ws + wxoff);
  double* partial = (double*)(ws + WS_PART);
  const int lane = threadIdx.x & 63;
  const int wid = blockIdx.x * 4 + (threadIdx.x >> 6);   // 0..1023
  int M = *(const int*)(ws + WS_CNT);
  if (M > wlcap) M = wlcap;
  for (int i = wid; i < M; i += 1024) {
    const int p = wlist[i];
    const int n = p >> 12, hw = p & 4095;
    const float* xp = in + (size_t)n * IMG + hw;
    float xv[DIM];
    if (i < wxcap) {
      const float* s = wx + (size_t)i * DIM;
#pragma unroll
      for (int j = 0; j < DIM; ++j) xv[j] = s[j];          // coalesced stash
    } else {
#pragma unroll
      for (int j = 0; j < DIM; ++j) xv[j] = xp[j * HW];    // strided fallback
    }
    float sx = 0.f;
#pragma unroll
    for (int j = 0; j < DIM; ++j) sx = fmaf(xv[j], xv[j], sx);
    float bd = INFINITY; int bki = 0;
#pragma unroll
    for (int m = 0; m < 8; ++m) {
      const int k = lane + 64 * m;
      const float* ek = emb + k * DIM;
      float a = 0.f;
#pragma unroll
      for (int j = 0; j < DIM; ++j) a = fmaf(xv[j], ek[j], a);
      const float d = (sx + se[k]) - 2.f * a;
      if (d < bd) { bd = d; bki = k; }                     // ascending k in-lane
    }
#pragma unroll
    for (int s = 1; s < 64; s <<= 1) {                     // lex-min (d, k)
      const float od = __shfl_xor(bd, s);
      const int   oi = __shfl_xor(bki, s);
      const bool t = (od < bd) || (od == bd && oi < bki);
      bd = t ? od : bd; bki = t ? oi : bki;
    }
    const int oldk = (int)out[IDX_OFF + p];
    if (bki != oldk) {
      const float xj = xv[lane];
      const float qn = emb[bki * DIM + lane];
      const float qo = emb[oldk * DIM + lane];
      out[(size_t)n * IMG + lane * HW + hw] = qn;
      const float dl = (qn - xj) * (qn - xj) - (qo - xj) * (qo - xj);
      double dd = (double)dl;
#pragma unroll
      for (int o = 32; o; o >>= 1) dd += __shfl_down(dd, o);
      if (lane == 0) {
        atomicAdd(&partial[0], dd);
        out[IDX_OFF + p] = (float)bki;
      }
    }
  }
}

// K4: finalize loss
__global__ void vq_loss(const double* __restrict__ partial, float* __restrict__ out) {
  __shared__ double r2[4];
  const int tid = threadIdx.x;
  double s = partial[tid] + partial[tid + 256];
#pragma unroll
  for (int o = 32; o; o >>= 1) s += __shfl_down(s, o);
  if ((tid & 63) == 0) r2[tid >> 6] = s;
  __syncthreads();
  if (tid == 0) {
    const double t = r2[0] + r2[1] + r2[2] + r2[3];
    out[LOSS_OFF] = (float)(0.25 * t / (double)OUT_Q);
  }
}

extern "C" void kernel_launch(void* const* d_in, const int* in_sizes, int n_in,
                              void* d_out, int out_size, void* d_ws, size_t ws_size,
                              hipStream_t stream) {
  (void)in_sizes; (void)n_in; (void)out_size;
  const float* in  = (const float*)d_in[0];
  const float* emb = (const float*)d_in[1];
  float* out = (float*)d_out;
  char* ws = (char*)d_ws;
  // capacity carving from ws_size (graceful degradation if scratch is tight)
  size_t avail = ws_size > WS_WL ? ws_size - WS_WL : 0;
  int wlcap = (int)(avail / 4 < 131072 ? avail / 4 : 131072);
  unsigned long long wxoff = WS_WL + (unsigned long long)wlcap * 4;
  size_t avail2 = ws_size > wxoff ? ws_size - wxoff : 0;
  size_t wxc = avail2 / (DIM * 4);
  int wxcap = (int)(wxc < (size_t)wlcap ? wxc : (size_t)wlcap);
  vq_prep<<<2,   256, 0, stream>>>(emb, ws);
  vq_main<<<512, 256, 0, stream>>>(in, emb, ws, out, wlcap, wxcap, wxoff);
  vq_fix <<<256, 256, 0, stream>>>(in, emb, ws, out, wlcap, wxcap, wxoff);
  vq_loss<<<1,   256, 0, stream>>>((const double*)(ws + WS_PART), out);
}

// Round 8
// 169.651 us; speedup vs baseline: 3.1145x; 1.5954x over previous
//
#include <hip/hip_runtime.h>
#include <math.h>

#define NUM_K 512
#define DIM   64
#define HW    4096
#define IMG   (DIM * HW)
#define OUT_Q 8388608
#define LOSS_OFF OUT_Q
#define IDX_OFF (OUT_Q + 1)
#define DELTA 8e-5f

// ws layout (bytes)
#define WS_EH   0        // bf16 hi codebook [512*64] = 64KB
#define WS_EL   65536    // bf16 lo codebook = 64KB
#define WS_SE   131072   // ||e||^2 f32 [512] = 2KB
#define WS_CNT  133120   // worklist counter (int) + pad = 256B
#define WS_PART 133376   // loss partials double[512] = 4KB
#define WS_ET   137472   // transposed codebook f32 [64][512] = 128KB
#define WS_WL   268544   // worklist pixel ids (cap from ws_size)

typedef float f32x4 __attribute__((ext_vector_type(4)));
typedef short s8v   __attribute__((ext_vector_type(8)));

__device__ inline short f2bf(float f) {  // RNE f32->bf16
  unsigned u = __float_as_uint(f);
  return (short)((u + 0x7FFF + ((u >> 16) & 1)) >> 16);
}
__device__ inline float bf2f(short s) {
  return __uint_as_float(((unsigned)(unsigned short)s) << 16);
}

// K1: split codebook to bf16 hi/lo, ||e||^2, transpose, zero counter
__global__ void vq_prep(const float* __restrict__ emb, char* __restrict__ ws) {
  short* eh = (short*)(ws + WS_EH);
  short* el = (short*)(ws + WS_EL);
  float* se = (float*)(ws + WS_SE);
  float* et = (float*)(ws + WS_ET);
  const int k = blockIdx.x * 256 + threadIdx.x;  // 0..511
  if (k == 0) *(int*)(ws + WS_CNT) = 0;
  const float* e = emb + k * DIM;
  float s = 0.f;
#pragma unroll
  for (int j = 0; j < DIM; ++j) {
    const float v = e[j];
    s = fmaf(v, v, s);
    const short h = f2bf(v);
    eh[k * DIM + j] = h;
    el[k * DIM + j] = f2bf(v - bf2f(h));
    et[j * NUM_K + k] = v;      // transposed copy (coalesced across k)
  }
  se[k] = s;
}

// K2: MFMA approx distances + min1/min2 + compaction + q/idx/loss + x-stash
__launch_bounds__(256, 2)
__global__ void vq_main(const float* __restrict__ in, const float* __restrict__ emb,
                        char* __restrict__ ws, float* __restrict__ out,
                        int wlcap, int wxcap, unsigned long long wxoff) {
  const short* eh = (const short*)(ws + WS_EH);
  const short* el = (const short*)(ws + WS_EL);
  const float* se = (const float*)(ws + WS_SE);
  int* wcnt  = (int*)(ws + WS_CNT);
  int* wlist = (int*)(ws + WS_WL);
  float* wx  = (float*)(ws + wxoff);
  double* partial = (double*)(ws + WS_PART);
  __shared__ int bkbuf[256];
  __shared__ int slotbuf[256];
  __shared__ unsigned char flg[256];
  __shared__ double red[4];

  const int tid = threadIdx.x;
  const int lane = tid & 63, w = tid >> 6;
  const int l15 = lane & 15, lh = lane >> 4;   // lh 0..3
  const int d0 = lh * 8;                        // lane's K-slice base
  const int pblk = blockIdx.x * 256;            // 256 contiguous pixels/block
  const int n = pblk >> 12;                     // uniform (256 | 4096)
  const int hwb = pblk & 4095;
  const int p0 = w * 64;                        // wave-local pixel base

  // ---- A-fragments: x[p0+rt*16+l15][h*32+d0+j] as bf16 hi/lo ----
  s8v ah[4][2], al[4][2];
#pragma unroll
  for (int rt = 0; rt < 4; ++rt) {
    const float* xp = in + (size_t)n * IMG + hwb + (p0 + rt * 16 + l15);
#pragma unroll
    for (int h = 0; h < 2; ++h) {
      s8v vh, vl;
#pragma unroll
      for (int j = 0; j < 8; ++j) {
        const float xv = xp[(h * 32 + d0 + j) * HW];
        const short hi = f2bf(xv);
        vh[j] = hi;
        vl[j] = f2bf(xv - bf2f(hi));
      }
      ah[rt][h] = vh; al[rt][h] = vl;
    }
  }

  // ---- 32 code-tiles of 16; packed (value|code) min1/min2 tracking ----
  float m1[4][4], m2[4][4];
#pragma unroll
  for (int rt = 0; rt < 4; ++rt)
#pragma unroll
    for (int r = 0; r < 4; ++r) { m1[rt][r] = INFINITY; m2[rt][r] = INFINITY; }

  for (int ct = 0; ct < 32; ++ct) {
    const int c = ct * 16 + l15;                 // this lane's code column
    const s8v beh0 = *(const s8v*)(eh + c * DIM + d0);
    const s8v beh1 = *(const s8v*)(eh + c * DIM + 32 + d0);
    const s8v bel0 = *(const s8v*)(el + c * DIM + d0);
    const s8v bel1 = *(const s8v*)(el + c * DIM + 32 + d0);
    const float sec = se[c];
#pragma unroll
    for (int rt = 0; rt < 4; ++rt) {
      f32x4 acc = {0.f, 0.f, 0.f, 0.f};
      acc = __builtin_amdgcn_mfma_f32_16x16x32_bf16(ah[rt][0], beh0, acc, 0, 0, 0);
      acc = __builtin_amdgcn_mfma_f32_16x16x32_bf16(ah[rt][1], beh1, acc, 0, 0, 0);
      acc = __builtin_amdgcn_mfma_f32_16x16x32_bf16(al[rt][0], beh0, acc, 0, 0, 0);
      acc = __builtin_amdgcn_mfma_f32_16x16x32_bf16(al[rt][1], beh1, acc, 0, 0, 0);
      acc = __builtin_amdgcn_mfma_f32_16x16x32_bf16(ah[rt][0], bel0, acc, 0, 0, 0);
      acc = __builtin_amdgcn_mfma_f32_16x16x32_bf16(ah[rt][1], bel1, acc, 0, 0, 0);
#pragma unroll
      for (int r = 0; r < 4; ++r) {
        const float cv = fmaf(-2.f, acc[r], sec);          // se - 2*dot
        const float pk = __int_as_float((__float_as_int(cv) & 0xFFFFFE00) | c);
        m2[rt][r] = fminf(m2[rt][r], fmaxf(m1[rt][r], pk));
        m1[rt][r] = fminf(m1[rt][r], pk);
      }
    }
  }

  // ---- reduce min1/min2 across the 16 code-column lanes ----
#pragma unroll
  for (int s = 1; s < 16; s <<= 1) {
#pragma unroll
    for (int rt = 0; rt < 4; ++rt)
#pragma unroll
      for (int r = 0; r < 4; ++r) {
        const float o1 = __shfl_xor(m1[rt][r], s);
        const float o2 = __shfl_xor(m2[rt][r], s);
        const float hi = fmaxf(m1[rt][r], o1);
        m1[rt][r] = fminf(m1[rt][r], o1);
        m2[rt][r] = fminf(fminf(m2[rt][r], o2), hi);
      }
  }
  if (l15 == 0) {
#pragma unroll
    for (int rt = 0; rt < 4; ++rt)
#pragma unroll
      for (int r = 0; r < 4; ++r) {
        const int lp = p0 + rt * 16 + lh * 4 + r;          // C-row pixel
        bkbuf[lp] = __float_as_int(m1[rt][r]) & 511;
        flg[lp] = (m2[rt][r] - m1[rt][r] <= DELTA) ? 1 : 0;
      }
  }
  __syncthreads();

  // ---- compaction: one atomicAdd per wave, slot per flagged pixel ----
  {
    const bool f = flg[tid] != 0;
    const unsigned long long b = __ballot(f);
    const int cnt = __popcll(b);
    int base = 0;
    if (cnt) {
      if (lane == 0) base = atomicAdd(wcnt, cnt);
      base = __shfl(base, 0);
    }
    int sl = -1;
    if (f) {
      const int pos = base + __popcll(b & ((1ull << lane) - 1));
      if (pos < wlcap) { sl = pos; wlist[pos] = pblk + tid; }
    }
    slotbuf[tid] = sl;
  }
  __syncthreads();

  // ---- epilogue: gather q, write q/idx, loss partial, stash flagged x ----
  float ls = 0.f;
#pragma unroll
  for (int rt = 0; rt < 4; ++rt) {
    const int lp = p0 + rt * 16 + l15;
    const int bk = bkbuf[lp];
    const int sl = slotbuf[lp];
    if (lh == 0) out[IDX_OFF + pblk + lp] = (float)bk;
    const float* ep = emb + bk * DIM;
    const float* xp = in  + (size_t)n * IMG + hwb + lp;
    float*       op = out + (size_t)n * IMG + hwb + lp;
#pragma unroll
    for (int h = 0; h < 2; ++h)
#pragma unroll
      for (int j = 0; j < 8; ++j) {
        const int d = h * 32 + d0 + j;
        const float q = ep[d];
        const float xv = xp[d * HW];
        op[d * HW] = q;
        if (sl >= 0 && sl < wxcap) wx[(size_t)sl * DIM + d] = xv;
        const float dd = q - xv;
        ls = fmaf(dd, dd, ls);
      }
  }
  double dls = (double)ls;
#pragma unroll
  for (int o = 32; o; o >>= 1) dls += __shfl_down(dls, o);
  if (lane == 0) red[w] = dls;
  __syncthreads();
  if (tid == 0) partial[blockIdx.x] = red[0] + red[1] + red[2] + red[3];
}

// K3: exact fp32 rerank, one THREAD per code, one block (512 thr) per pixel.
// Transposed codebook -> coalesced; x via LDS broadcast; no big per-lane arrays.
__launch_bounds__(512)
__global__ void vq_fix(const float* __restrict__ in, const float* __restrict__ emb,
                       char* __restrict__ ws, float* __restrict__ out,
                       int wlcap, int wxcap, unsigned long long wxoff) {
  const float* se = (const float*)(ws + WS_SE);
  const float* et = (const float*)(ws + WS_ET);
  const int* wlist = (const int*)(ws + WS_WL);
  const float* wx = (const float*)(ws + wxoff);
  double* partial = (double*)(ws + WS_PART);
  __shared__ float xs[DIM];
  __shared__ float pd[8];
  __shared__ int   pkk[8];
  __shared__ int   sbk;

  const int tid = threadIdx.x;          // == code id t
  const int lane = tid & 63, w = tid >> 6;
  int M = *(const int*)(ws + WS_CNT);
  if (M > wlcap) M = wlcap;

  for (int i = blockIdx.x; i < M; i += gridDim.x) {
    const int p = wlist[i];
    const int n = p >> 12, hw = p & 4095;
    if (tid < DIM) {
      xs[tid] = (i < wxcap) ? wx[(size_t)i * DIM + tid]
                            : in[(size_t)n * IMG + (size_t)tid * HW + hw];
    }
    __syncthreads();

    // proven chains: sx and dot both j-ascending sequential fp32
    float sx = 0.f, a = 0.f;
#pragma unroll 8
    for (int j = 0; j < DIM; ++j) {
      const float xj = xs[j];                       // LDS broadcast
      sx = fmaf(xj, xj, sx);
      a  = fmaf(xj, et[j * NUM_K + tid], a);        // coalesced across tid
    }
    float bd = (sx + se[tid]) - 2.f * a;
    int bki = tid;
    // in-wave lex-min (d, k)
#pragma unroll
    for (int s = 1; s < 64; s <<= 1) {
      const float od = __shfl_xor(bd, s);
      const int   oi = __shfl_xor(bki, s);
      const bool t = (od < bd) || (od == bd && oi < bki);
      bd = t ? od : bd; bki = t ? oi : bki;
    }
    if (lane == 0) { pd[w] = bd; pkk[w] = bki; }
    __syncthreads();
    if (tid == 0) {
      float fb = pd[0]; int fk = pkk[0];
#pragma unroll
      for (int q = 1; q < 8; ++q) {                 // ascending k: strict <
        if (pd[q] < fb) { fb = pd[q]; fk = pkk[q]; }
      }
      sbk = fk;
    }
    __syncthreads();
    const int bkn = sbk;
    const int oldk = (int)out[IDX_OFF + p];
    if (bkn != oldk) {
      if (tid < DIM) {
        const float xj = xs[tid];
        const float qn = emb[bkn  * DIM + tid];
        const float qo = emb[oldk * DIM + tid];
        out[(size_t)n * IMG + (size_t)tid * HW + hw] = qn;
        const float dl = (qn - xj) * (qn - xj) - (qo - xj) * (qo - xj);
        double dd = (double)dl;
#pragma unroll
        for (int o = 32; o; o >>= 1) dd += __shfl_down(dd, o);
        if (tid == 0) {
          atomicAdd(&partial[0], dd);
          out[IDX_OFF + p] = (float)bkn;
        }
      }
    }
    __syncthreads();   // protect xs before next iteration
  }
}

// K4: finalize loss
__global__ void vq_loss(const double* __restrict__ partial, float* __restrict__ out) {
  __shared__ double r2[4];
  const int tid = threadIdx.x;
  double s = partial[tid] + partial[tid + 256];
#pragma unroll
  for (int o = 32; o; o >>= 1) s += __shfl_down(s, o);
  if ((tid & 63) == 0) r2[tid >> 6] = s;
  __syncthreads();
  if (tid == 0) {
    const double t = r2[0] + r2[1] + r2[2] + r2[3];
    out[LOSS_OFF] = (float)(0.25 * t / (double)OUT_Q);
  }
}

extern "C" void kernel_launch(void* const* d_in, const int* in_sizes, int n_in,
                              void* d_out, int out_size, void* d_ws, size_t ws_size,
                              hipStream_t stream) {
  (void)in_sizes; (void)n_in; (void)out_size;
  const float* in  = (const float*)d_in[0];
  const float* emb = (const float*)d_in[1];
  float* out = (float*)d_out;
  char* ws = (char*)d_ws;
  // capacity carving from ws_size (graceful degradation if scratch is tight)
  size_t avail = ws_size > WS_WL ? ws_size - WS_WL : 0;
  int wlcap = (int)(avail / 4 < 131072 ? avail / 4 : 131072);
  unsigned long long wxoff = WS_WL + (unsigned long long)wlcap * 4;
  size_t avail2 = ws_size > wxoff ? ws_size - wxoff : 0;
  size_t wxc = avail2 / (DIM * 4);
  int wxcap = (int)(wxc < (size_t)wlcap ? wxc : (size_t)wlcap);
  vq_prep<<<2,    256, 0, stream>>>(emb, ws);
  vq_main<<<512,  256, 0, stream>>>(in, emb, ws, out, wlcap, wxcap, wxoff);
  vq_fix <<<2048, 512, 0, stream>>>(in, emb, ws, out, wlcap, wxcap, wxoff);
  vq_loss<<<1,    256, 0, stream>>>((const double*)(ws + WS_PART), out);
}